// Round 1
// baseline (653.269 us; speedup 1.0000x reference)
//
#include <hip/hip_runtime.h>

typedef _Float16 f16;
typedef f16 f16x2 __attribute__((ext_vector_type(2)));
typedef f16 f16x4 __attribute__((ext_vector_type(4)));
typedef f16 f16x8 __attribute__((ext_vector_type(8)));
typedef float floatx4 __attribute__((ext_vector_type(4)));

#define LDS_AS(p) ((__attribute__((address_space(3))) unsigned int*)(p))
#define GLB_AS(p) ((const __attribute__((address_space(1))) unsigned int*)(p))

__device__ __forceinline__ void gload16(const void* g, void* l) {
  __builtin_amdgcn_global_load_lds(GLB_AS(g), LDS_AS(l), 16, 0, 0);
}

// ---------------------------------------------------------------------------
// Kernel 1: convert proj_w fp32 -> fp16 (512*512 elements)
// ---------------------------------------------------------------------------
__global__ __launch_bounds__(256) void wconv_kernel(const float* __restrict__ w,
                                                    f16* __restrict__ wh) {
  const int i = (blockIdx.x * 256 + threadIdx.x) * 4;
  const float4 v = *(const float4*)(w + i);
  f16x4 o;
  o.x = (f16)v.x; o.y = (f16)v.y; o.z = (f16)v.z; o.w = (f16)v.w;
  *(f16x4*)(wh + i) = o;
}

// ---------------------------------------------------------------------------
// Kernel 2: windowed cosine attention. One block = one (window, head).
// grid = B*nH*nW*Hh = 4*16*16*8 = 8192 blocks, 256 threads (4 waves).
// Output X: (65536 pixels, 512 channels) fp16, pixel-major.
// ---------------------------------------------------------------------------
__global__ __launch_bounds__(256) void attn_kernel(
    const float* __restrict__ qkv, const float* __restrict__ logit_scale,
    const float* __restrict__ rpb, const int* __restrict__ rel_index,
    f16* __restrict__ X) {
  // stride 72 f16 = 144 B per row: 16B-aligned rows for ds_read_b128
  __shared__ f16 qs[64 * 72];   // [token][channel]
  __shared__ f16 ks[64 * 72];   // [token][channel]
  __shared__ f16 vs[64 * 72];   // [channel][token]  (transposed for PV B-frag)
  __shared__ f16 ps[64 * 72];   // [q-token][k-token]
  __shared__ float partial[4][64];

  const int bid = blockIdx.x;
  const int h   = bid & 7;
  const int win = bid >> 3;
  const int wx  = win & 15;
  const int wy  = (win >> 4) & 15;
  const int b   = win >> 8;

  const int tid  = threadIdx.x;
  const int wave = tid >> 6;
  const int lane = tid & 63;

  // ---- phase 1: load q,k fp32, L2-normalize, store f16; load v -> vs[d][a]
  {
    const int a  = lane;                    // token
    const int ty = a >> 3, tx = a & 7;
    const int poff = (wy * 8 + ty) * 128 + wx * 8 + tx;
    const size_t headbase = (size_t)((b * 8 + h) * 192) * 16384 + poff;
    const int cbase = (wave & 1) * 32;      // channel sub-range per wave
    const int qk = (wave < 2) ? 0 : 64;     // waves 0,1 -> q; 2,3 -> k
    const float* src = qkv + headbase + (size_t)(qk + cbase) * 16384;
    float vals[32];
    float ssq = 0.f;
#pragma unroll
    for (int i = 0; i < 32; i++) {
      float v = src[(size_t)i * 16384];
      vals[i] = v;
      ssq += v * v;
    }
    partial[wave][a] = ssq;

    const float* vsrc = qkv + headbase + (size_t)(128 + wave * 16) * 16384;
    float vv[16];
#pragma unroll
    for (int i = 0; i < 16; i++) vv[i] = vsrc[(size_t)i * 16384];

    __syncthreads();
    const float tot = partial[wave & 2][a] + partial[(wave & 2) | 1][a];
    const float rs = 1.0f / fmaxf(sqrtf(tot), 1e-12f);
    f16* dst = ((wave < 2) ? qs : ks) + a * 72 + cbase;
#pragma unroll
    for (int i = 0; i < 16; i++) {
      f16x2 pr;
      pr.x = (f16)(vals[2 * i] * rs);
      pr.y = (f16)(vals[2 * i + 1] * rs);
      *(f16x2*)(dst + 2 * i) = pr;
    }
#pragma unroll
    for (int i = 0; i < 16; i++) vs[(wave * 16 + i) * 72 + a] = (f16)vv[i];
  }
  __syncthreads();

  // ---- phase 2: S = scale*(Q K^T) + bias; row softmax; -> ps (f16)
  const int fr = lane & 15;   // fragment row/col index
  const int g  = lane >> 4;   // k-slice group
  const int m0 = wave * 16;   // this wave's q-token block
  const float scale = __expf(fminf(logit_scale[h], 4.60517019f));  // ln(100)

  floatx4 acc[4];
  {
    const f16x8 a0 = *(const f16x8*)(qs + (m0 + fr) * 72 + g * 8);
    const f16x8 a1 = *(const f16x8*)(qs + (m0 + fr) * 72 + 32 + g * 8);
#pragma unroll
    for (int nt = 0; nt < 4; nt++) {
      const f16x8 b0 = *(const f16x8*)(ks + (nt * 16 + fr) * 72 + g * 8);
      const f16x8 b1 = *(const f16x8*)(ks + (nt * 16 + fr) * 72 + 32 + g * 8);
      floatx4 z = {0.f, 0.f, 0.f, 0.f};
      z = __builtin_amdgcn_mfma_f32_16x16x32_f16(a0, b0, z, 0, 0, 0);
      z = __builtin_amdgcn_mfma_f32_16x16x32_f16(a1, b1, z, 0, 0, 0);
      acc[nt] = z;
    }
  }

#pragma unroll
  for (int r = 0; r < 4; r++) {
    const int m = m0 + g * 4 + r;   // C-layout row
    float v0[4];
    float mx = -1e30f;
#pragma unroll
    for (int nt = 0; nt < 4; nt++) {
      const int n = nt * 16 + fr;   // C-layout col
      const float val = acc[nt][r] * scale + rpb[rel_index[m * 64 + n] * 8 + h];
      v0[nt] = val;
      mx = fmaxf(mx, val);
    }
    mx = fmaxf(mx, __shfl_xor(mx, 1));
    mx = fmaxf(mx, __shfl_xor(mx, 2));
    mx = fmaxf(mx, __shfl_xor(mx, 4));
    mx = fmaxf(mx, __shfl_xor(mx, 8));
    float s = 0.f;
#pragma unroll
    for (int nt = 0; nt < 4; nt++) {
      v0[nt] = __expf(v0[nt] - mx);
      s += v0[nt];
    }
    s += __shfl_xor(s, 1);
    s += __shfl_xor(s, 2);
    s += __shfl_xor(s, 4);
    s += __shfl_xor(s, 8);
    const float rinv = 1.0f / s;
#pragma unroll
    for (int nt = 0; nt < 4; nt++)
      ps[m * 72 + nt * 16 + fr] = (f16)(v0[nt] * rinv);
  }

  // ---- phase 3: O = P V. ps rows m0..m0+15 written by THIS wave only ->
  // no barrier needed (compiler orders same-wave ds_write/ds_read via lgkmcnt).
  floatx4 oacc[4];
  {
    const f16x8 pa0 = *(const f16x8*)(ps + (m0 + fr) * 72 + g * 8);
    const f16x8 pa1 = *(const f16x8*)(ps + (m0 + fr) * 72 + 32 + g * 8);
#pragma unroll
    for (int dt = 0; dt < 4; dt++) {
      const f16x8 vb0 = *(const f16x8*)(vs + (dt * 16 + fr) * 72 + g * 8);
      const f16x8 vb1 = *(const f16x8*)(vs + (dt * 16 + fr) * 72 + 32 + g * 8);
      floatx4 z = {0.f, 0.f, 0.f, 0.f};
      z = __builtin_amdgcn_mfma_f32_16x16x32_f16(pa0, vb0, z, 0, 0, 0);
      z = __builtin_amdgcn_mfma_f32_16x16x32_f16(pa1, vb1, z, 0, 0, 0);
      oacc[dt] = z;
    }
  }

#pragma unroll
  for (int r = 0; r < 4; r++) {
    const int m = m0 + g * 4 + r;
    const int ty = m >> 3, tx = m & 7;
    const size_t npix = (size_t)(b * 128 + wy * 8 + ty) * 128 + wx * 8 + tx;
    f16* xp = X + npix * 512 + h * 64;
#pragma unroll
    for (int dt = 0; dt < 4; dt++) xp[dt * 16 + fr] = (f16)oacc[dt][r];
  }
}

// ---------------------------------------------------------------------------
// Kernel 3: projection GEMM. out[o][pix] = sum_c W[o][c] * X[pix][c] + b[o].
// M=512 (o), N=65536 (pix), K=512. 128x128 tiles, BK=32, m97-style staging.
// grid = 4 o-tiles * 512 pix-tiles = 2048 (o-tile fastest for X-tile L2 reuse)
// ---------------------------------------------------------------------------
__global__ __launch_bounds__(256) void proj_kernel(
    const f16* __restrict__ Wh, const f16* __restrict__ X,
    const float* __restrict__ bias, float* __restrict__ out) {
  __shared__ f16 As[128 * 32];  // W tile   [o-local][c-local]
  __shared__ f16 Bs[128 * 32];  // X tile   [pix-local][c-local]

  const int tid  = threadIdx.x;
  const int lane = tid & 63;
  const int wave = tid >> 6;
  const int o0 = (blockIdx.x & 3) * 128;
  const int p0 = (blockIdx.x >> 2) * 128;

  const int fr = lane & 15, g = lane >> 4;
  const int wr = wave >> 1, wc = wave & 1;

  floatx4 acc[4][4] = {};

  // staging chunk mapping: thread t covers (row = t/4, c = (t%4)*8) and row+64
  const int r0 = tid >> 2;
  const int c0 = (tid & 3) * 8;
  const f16* gA0 = Wh + (size_t)(o0 + r0) * 512 + c0;
  const f16* gA1 = Wh + (size_t)(o0 + 64 + r0) * 512 + c0;
  const f16* gB0 = X + (size_t)(p0 + r0) * 512 + c0;
  const f16* gB1 = X + (size_t)(p0 + 64 + r0) * 512 + c0;
  f16* lA0 = As + tid * 8;
  f16* lA1 = As + (256 + tid) * 8;
  f16* lB0 = Bs + tid * 8;
  f16* lB1 = Bs + (256 + tid) * 8;

  for (int kc = 0; kc < 512; kc += 32) {
    gload16(gA0 + kc, lA0);
    gload16(gA1 + kc, lA1);
    gload16(gB0 + kc, lB0);
    gload16(gB1 + kc, lB1);
    __syncthreads();   // drains vmcnt -> LDS tiles ready
    f16x8 af[4], bfr[4];
#pragma unroll
    for (int mt = 0; mt < 4; mt++)
      af[mt] = *(const f16x8*)(As + (wr * 64 + mt * 16 + fr) * 32 + g * 8);
#pragma unroll
    for (int nt = 0; nt < 4; nt++)
      bfr[nt] = *(const f16x8*)(Bs + (wc * 64 + nt * 16 + fr) * 32 + g * 8);
#pragma unroll
    for (int mt = 0; mt < 4; mt++)
#pragma unroll
      for (int nt = 0; nt < 4; nt++)
        acc[mt][nt] = __builtin_amdgcn_mfma_f32_16x16x32_f16(af[mt], bfr[nt],
                                                             acc[mt][nt], 0, 0, 0);
    __syncthreads();   // protect LDS before next-iter overwrite
  }

  // epilogue: pix tile p0..p0+127 lies in one (b, y) row -> coalesced stores
  const int bidx = p0 >> 14;
  const int rem0 = p0 & 16383;
#pragma unroll
  for (int mt = 0; mt < 4; mt++) {
#pragma unroll
    for (int r = 0; r < 4; r++) {
      const int o = o0 + wr * 64 + mt * 16 + g * 4 + r;
      const float bv = bias[o];
      float* op = out + ((size_t)(bidx * 512 + o) << 14) + rem0 + wc * 64;
#pragma unroll
      for (int nt = 0; nt < 4; nt++) op[nt * 16 + fr] = acc[mt][nt][r] + bv;
    }
  }
}

// ---------------------------------------------------------------------------
extern "C" void kernel_launch(void* const* d_in, const int* in_sizes, int n_in,
                              void* d_out, int out_size, void* d_ws, size_t ws_size,
                              hipStream_t stream) {
  const float* qkv         = (const float*)d_in[0];
  const float* logit_scale = (const float*)d_in[1];
  const float* rpb         = (const float*)d_in[2];
  const float* proj_w      = (const float*)d_in[3];
  const float* proj_b      = (const float*)d_in[4];
  const int*   rel_index   = (const int*)d_in[5];
  float* out = (float*)d_out;

  f16* Wh = (f16*)d_ws;                           // 512*512*2   = 512 KiB
  f16* X  = (f16*)((char*)d_ws + (512 * 512 * 2)); // 65536*512*2 = 64 MiB

  hipLaunchKernelGGL(wconv_kernel, dim3(256), dim3(256), 0, stream, proj_w, Wh);
  hipLaunchKernelGGL(attn_kernel, dim3(8192), dim3(256), 0, stream,
                     qkv, logit_scale, rpb, rel_index, X);
  hipLaunchKernelGGL(proj_kernel, dim3(2048), dim3(256), 0, stream,
                     Wh, X, proj_b, out);
}

// Round 2
// 643.566 us; speedup vs baseline: 1.0151x; 1.0151x over previous
//
#include <hip/hip_runtime.h>

typedef _Float16 f16;
typedef f16 f16x2 __attribute__((ext_vector_type(2)));
typedef f16 f16x4 __attribute__((ext_vector_type(4)));
typedef f16 f16x8 __attribute__((ext_vector_type(8)));
typedef float floatx4 __attribute__((ext_vector_type(4)));

#define LDS_AS(p) ((__attribute__((address_space(3))) unsigned int*)(p))
#define GLB_AS(p) ((const __attribute__((address_space(1))) unsigned int*)(p))

__device__ __forceinline__ void gload16(const void* g, void* l) {
  __builtin_amdgcn_global_load_lds(GLB_AS(g), LDS_AS(l), 16, 0, 0);
}

// ---------------------------------------------------------------------------
// Kernel 1: convert proj_w fp32 -> fp16 (512*512 elements)
// ---------------------------------------------------------------------------
__global__ __launch_bounds__(256) void wconv_kernel(const float* __restrict__ w,
                                                    f16* __restrict__ wh) {
  const int i = (blockIdx.x * 256 + threadIdx.x) * 4;
  const float4 v = *(const float4*)(w + i);
  f16x4 o;
  o.x = (f16)v.x; o.y = (f16)v.y; o.z = (f16)v.z; o.w = (f16)v.w;
  *(f16x4*)(wh + i) = o;
}

// ---------------------------------------------------------------------------
// Kernel 2: windowed cosine attention. One block = one (window, head).
// grid = 8192 blocks, 256 threads (4 waves).
// Phase 1a: float4 global loads (4x fewer instructions than scalar), raw f16
//           into LDS; V written directly transposed.
// Phase 1b: LDS-local L2-normalization of q,k (128 threads each).
// Phase 2/3: identical to validated R1 (MFMA QK^T, softmax, PV).
// ---------------------------------------------------------------------------
__global__ __launch_bounds__(256) void attn_kernel(
    const float* __restrict__ qkv, const float* __restrict__ logit_scale,
    const float* __restrict__ rpb, const int* __restrict__ rel_index,
    f16* __restrict__ X) {
  __shared__ f16 qs[64 * 72];   // [token][channel]  stride 72 (144B, 16B-mult)
  __shared__ f16 ks[64 * 72];   // [token][channel]
  __shared__ f16 vs[64 * 72];   // [channel][token]  (transposed for PV B-frag)
  __shared__ f16 ps[64 * 72];   // [q-token][k-token]

  const int bid = blockIdx.x;
  const int h   = bid & 7;
  const int win = bid >> 3;
  const int wx  = win & 15;
  const int wy  = (win >> 4) & 15;
  const int b   = win >> 8;

  const int tid  = threadIdx.x;
  const int wave = tid >> 6;
  const int lane = tid & 63;

  // ---- phase 1a: vectorized loads. thread = (channel c, quad)
  {
    const int c    = tid >> 2;        // 0..63
    const int quad = tid & 3;
    const int xh   = quad & 1;        // which float4 of the 8-px row
    const int tyb  = quad >> 1;
    const size_t base = (size_t)((b * 8 + h) * 192) * 16384 +
                        (size_t)(wy * 8) * 128 + wx * 8 + xh * 4;
    const float* qp = qkv + base + (size_t)c * 16384;
    const float* kp = qkv + base + (size_t)(64 + c) * 16384;
    const float* vp = qkv + base + (size_t)(128 + c) * 16384;
#pragma unroll
    for (int j = 0; j < 4; j++) {
      const int ty = 2 * j + tyb;
      const int t0 = ty * 8 + xh * 4;      // first of 4 consecutive tokens
      const float4 qv = *(const float4*)(qp + ty * 128);
      const float4 kv = *(const float4*)(kp + ty * 128);
      const float4 vv = *(const float4*)(vp + ty * 128);
      qs[(t0 + 0) * 72 + c] = (f16)qv.x;
      qs[(t0 + 1) * 72 + c] = (f16)qv.y;
      qs[(t0 + 2) * 72 + c] = (f16)qv.z;
      qs[(t0 + 3) * 72 + c] = (f16)qv.w;
      ks[(t0 + 0) * 72 + c] = (f16)kv.x;
      ks[(t0 + 1) * 72 + c] = (f16)kv.y;
      ks[(t0 + 2) * 72 + c] = (f16)kv.z;
      ks[(t0 + 3) * 72 + c] = (f16)kv.w;
      vs[c * 72 + t0 + 0] = (f16)vv.x;     // direct transpose
      vs[c * 72 + t0 + 1] = (f16)vv.y;
      vs[c * 72 + t0 + 2] = (f16)vv.z;
      vs[c * 72 + t0 + 3] = (f16)vv.w;
    }
  }
  __syncthreads();

  // ---- phase 1b: L2-normalize q (tid<128) and k (tid>=128) in place
  {
    const int token = (tid & 127) >> 1;
    const int half  = tid & 1;
    f16* rowp = ((tid < 128) ? qs : ks) + token * 72 + half * 32;
    f16x8 d[4];
    float ssq = 0.f;
#pragma unroll
    for (int i = 0; i < 4; i++) {
      d[i] = *(const f16x8*)(rowp + i * 8);
#pragma unroll
      for (int e = 0; e < 8; e++) {
        const float f = (float)d[i][e];
        ssq += f * f;
      }
    }
    ssq += __shfl_xor(ssq, 1);   // pairs (2t,2t+1) stay within a wave
    const float rs = 1.0f / fmaxf(sqrtf(ssq), 1e-12f);
#pragma unroll
    for (int i = 0; i < 4; i++) {
#pragma unroll
      for (int e = 0; e < 8; e++) d[i][e] = (f16)((float)d[i][e] * rs);
      *(f16x8*)(rowp + i * 8) = d[i];
    }
  }
  __syncthreads();

  // ---- phase 2: S = scale*(Q K^T) + bias; row softmax; -> ps (f16)
  const int fr = lane & 15;
  const int g  = lane >> 4;
  const int m0 = wave * 16;
  const float scale = __expf(fminf(logit_scale[h], 4.60517019f));  // ln(100)

  floatx4 acc[4];
  {
    const f16x8 a0 = *(const f16x8*)(qs + (m0 + fr) * 72 + g * 8);
    const f16x8 a1 = *(const f16x8*)(qs + (m0 + fr) * 72 + 32 + g * 8);
#pragma unroll
    for (int nt = 0; nt < 4; nt++) {
      const f16x8 b0 = *(const f16x8*)(ks + (nt * 16 + fr) * 72 + g * 8);
      const f16x8 b1 = *(const f16x8*)(ks + (nt * 16 + fr) * 72 + 32 + g * 8);
      floatx4 z = {0.f, 0.f, 0.f, 0.f};
      z = __builtin_amdgcn_mfma_f32_16x16x32_f16(a0, b0, z, 0, 0, 0);
      z = __builtin_amdgcn_mfma_f32_16x16x32_f16(a1, b1, z, 0, 0, 0);
      acc[nt] = z;
    }
  }

#pragma unroll
  for (int r = 0; r < 4; r++) {
    const int m = m0 + g * 4 + r;   // C-layout row
    float v0[4];
    float mx = -1e30f;
#pragma unroll
    for (int nt = 0; nt < 4; nt++) {
      const int n = nt * 16 + fr;   // C-layout col
      const float val = acc[nt][r] * scale + rpb[rel_index[m * 64 + n] * 8 + h];
      v0[nt] = val;
      mx = fmaxf(mx, val);
    }
    mx = fmaxf(mx, __shfl_xor(mx, 1));
    mx = fmaxf(mx, __shfl_xor(mx, 2));
    mx = fmaxf(mx, __shfl_xor(mx, 4));
    mx = fmaxf(mx, __shfl_xor(mx, 8));
    float s = 0.f;
#pragma unroll
    for (int nt = 0; nt < 4; nt++) {
      v0[nt] = __expf(v0[nt] - mx);
      s += v0[nt];
    }
    s += __shfl_xor(s, 1);
    s += __shfl_xor(s, 2);
    s += __shfl_xor(s, 4);
    s += __shfl_xor(s, 8);
    const float rinv = 1.0f / s;
#pragma unroll
    for (int nt = 0; nt < 4; nt++)
      ps[m * 72 + nt * 16 + fr] = (f16)(v0[nt] * rinv);
  }

  // ---- phase 3: O = P V (ps rows m0..m0+15 written by THIS wave only)
  floatx4 oacc[4];
  {
    const f16x8 pa0 = *(const f16x8*)(ps + (m0 + fr) * 72 + g * 8);
    const f16x8 pa1 = *(const f16x8*)(ps + (m0 + fr) * 72 + 32 + g * 8);
#pragma unroll
    for (int dt = 0; dt < 4; dt++) {
      const f16x8 vb0 = *(const f16x8*)(vs + (dt * 16 + fr) * 72 + g * 8);
      const f16x8 vb1 = *(const f16x8*)(vs + (dt * 16 + fr) * 72 + 32 + g * 8);
      floatx4 z = {0.f, 0.f, 0.f, 0.f};
      z = __builtin_amdgcn_mfma_f32_16x16x32_f16(pa0, vb0, z, 0, 0, 0);
      z = __builtin_amdgcn_mfma_f32_16x16x32_f16(pa1, vb1, z, 0, 0, 0);
      oacc[dt] = z;
    }
  }

#pragma unroll
  for (int r = 0; r < 4; r++) {
    const int m = m0 + g * 4 + r;
    const int ty = m >> 3, tx = m & 7;
    const size_t npix = (size_t)(b * 128 + wy * 8 + ty) * 128 + wx * 8 + tx;
    f16* xp = X + npix * 512 + h * 64;
#pragma unroll
    for (int dt = 0; dt < 4; dt++) xp[dt * 16 + fr] = (f16)oacc[dt][r];
  }
}

// ---------------------------------------------------------------------------
// Kernel 3: projection GEMM. out[o][pix] = sum_c W[o][c] * X[pix][c] + b[o].
// M=512, N=65536, K=512. 128x128 tiles, BK=64 (8 iters, barriers halved).
// XOR-swizzled LDS chunk layout (applied to the GLOBAL source index, so the
// lane-linear global_load_lds destination is preserved): chunk c8 of row r
// lives at slot c8^(r&7). Frag-read banks: ((kk*4+g)^(fr&7))*4 -> all 32
// banks, 2-way aliasing = free (was 8-way conflicted at BK=32 unswizzled).
// ---------------------------------------------------------------------------
__global__ __launch_bounds__(256) void proj_kernel(
    const f16* __restrict__ Wh, const f16* __restrict__ X,
    const float* __restrict__ bias, float* __restrict__ out) {
  __shared__ f16 As[128 * 64];  // W tile [o-local][c-local], swizzled
  __shared__ f16 Bs[128 * 64];  // X tile [pix-local][c-local], swizzled

  const int tid  = threadIdx.x;
  const int lane = tid & 63;
  const int wave = tid >> 6;
  const int o0 = (blockIdx.x & 3) * 128;
  const int p0 = (blockIdx.x >> 2) * 128;

  const int fr = lane & 15, g = lane >> 4;
  const int wr = wave >> 1, wc = wave & 1;

  floatx4 acc[4][4] = {};

  // staging: chunk j covers slot = j*256 + tid; row = slot>>3; stored chunk
  // c8 = (tid&7) ^ (row&7). 8 consecutive lanes read one row's 8 chunks
  // permuted -> still one 128B coalesced region.
  const f16* gA[4];
  const f16* gB[4];
#pragma unroll
  for (int j = 0; j < 4; j++) {
    const int slot = j * 256 + tid;
    const int row  = slot >> 3;
    const int c8   = (tid & 7) ^ (row & 7);
    gA[j] = Wh + (size_t)(o0 + row) * 512 + c8 * 8;
    gB[j] = X  + (size_t)(p0 + row) * 512 + c8 * 8;
  }

  for (int kc = 0; kc < 512; kc += 64) {
#pragma unroll
    for (int j = 0; j < 4; j++) {
      gload16(gA[j] + kc, As + (j * 256 + tid) * 8);
      gload16(gB[j] + kc, Bs + (j * 256 + tid) * 8);
    }
    __syncthreads();   // drains vmcnt -> LDS tiles ready
#pragma unroll
    for (int kk = 0; kk < 2; kk++) {
      f16x8 af[4], bfr[4];
#pragma unroll
      for (int mt = 0; mt < 4; mt++) {
        const int row = wr * 64 + mt * 16 + fr;
        af[mt] = *(const f16x8*)(As + row * 64 + (((kk * 4 + g) ^ (row & 7)) * 8));
      }
#pragma unroll
      for (int nt = 0; nt < 4; nt++) {
        const int row = wc * 64 + nt * 16 + fr;
        bfr[nt] = *(const f16x8*)(Bs + row * 64 + (((kk * 4 + g) ^ (row & 7)) * 8));
      }
#pragma unroll
      for (int mt = 0; mt < 4; mt++)
#pragma unroll
        for (int nt = 0; nt < 4; nt++)
          acc[mt][nt] = __builtin_amdgcn_mfma_f32_16x16x32_f16(af[mt], bfr[nt],
                                                               acc[mt][nt], 0, 0, 0);
    }
    __syncthreads();   // protect LDS before next-iter overwrite
  }

  // epilogue: pix tile p0..p0+127 lies in one (b, y) row -> coalesced stores
  const int bidx = p0 >> 14;
  const int rem0 = p0 & 16383;
#pragma unroll
  for (int mt = 0; mt < 4; mt++) {
#pragma unroll
    for (int r = 0; r < 4; r++) {
      const int o = o0 + wr * 64 + mt * 16 + g * 4 + r;
      const float bv = bias[o];
      float* op = out + ((size_t)(bidx * 512 + o) << 14) + rem0 + wc * 64;
#pragma unroll
      for (int nt = 0; nt < 4; nt++) op[nt * 16 + fr] = acc[mt][nt][r] + bv;
    }
  }
}

// ---------------------------------------------------------------------------
extern "C" void kernel_launch(void* const* d_in, const int* in_sizes, int n_in,
                              void* d_out, int out_size, void* d_ws, size_t ws_size,
                              hipStream_t stream) {
  const float* qkv         = (const float*)d_in[0];
  const float* logit_scale = (const float*)d_in[1];
  const float* rpb         = (const float*)d_in[2];
  const float* proj_w      = (const float*)d_in[3];
  const float* proj_b      = (const float*)d_in[4];
  const int*   rel_index   = (const int*)d_in[5];
  float* out = (float*)d_out;

  f16* Wh = (f16*)d_ws;                            // 512*512*2   = 512 KiB
  f16* X  = (f16*)((char*)d_ws + (512 * 512 * 2)); // 65536*512*2 = 64 MiB

  hipLaunchKernelGGL(wconv_kernel, dim3(256), dim3(256), 0, stream, proj_w, Wh);
  hipLaunchKernelGGL(attn_kernel, dim3(8192), dim3(256), 0, stream,
                     qkv, logit_scale, rpb, rel_index, X);
  hipLaunchKernelGGL(proj_kernel, dim3(2048), dim3(256), 0, stream,
                     Wh, X, proj_b, out);
}